// Round 2
// baseline (908.059 us; speedup 1.0000x reference)
//
#include <hip/hip_runtime.h>

#define N_NODES 100000
#define N_EDGES 1600000
#define SCAN_NB ((N_NODES + 255) / 256)   // 391

// packed degree: bits 63..52 = count, bits 51..0 = sum(w) in 2^-32 fixed point
#define CNT_SHIFT 52
#define WSUM_MASK ((1ULL << 52) - 1)

typedef __attribute__((ext_vector_type(8))) short short8;   // MFMA A/B frag (8 bf16)
typedef __attribute__((ext_vector_type(4))) float f32x4;    // MFMA C/D frag

__device__ inline unsigned short f2bf(float f) {   // round-to-nearest-even
    unsigned int u = __float_as_uint(f);
    u += 0x7FFFu + ((u >> 16) & 1u);
    return (unsigned short)(u >> 16);
}
__device__ inline float bflo(unsigned int u) { return __uint_as_float(u << 16); }
__device__ inline float bfhi(unsigned int u) { return __uint_as_float(u & 0xFFFF0000u); }
__device__ inline float bf2f(unsigned short h) { return __uint_as_float((unsigned int)h << 16); }

// ---------------- CSR build ----------------

__global__ void init_packed_kernel(unsigned long long* __restrict__ packed, int n) {
    int i = blockIdx.x * blockDim.x + threadIdx.x;
    if (i < n) packed[i] = 1ULL << 32;   // self-loop weight 1.0, count 0
}

__global__ void edge_pass1_kernel(const int* __restrict__ dst, const float* __restrict__ w,
                                  unsigned long long* __restrict__ packed,
                                  int* __restrict__ rank, int E) {
    int e = blockIdx.x * blockDim.x + threadIdx.x;
    if (e < E) {
        int d = dst[e];
        unsigned long long inc = (1ULL << CNT_SHIFT)
                               + (unsigned long long)((double)w[e] * 4294967296.0);
        unsigned long long old = atomicAdd(&packed[d], inc);
        rank[e] = (int)(old >> CNT_SHIFT);
    }
}

// scan1 fused with extract: packed -> cnt, dinv, block sums
__global__ __launch_bounds__(256) void scan1_kernel(const unsigned long long* __restrict__ packed,
                                                    int* __restrict__ cnt, float* __restrict__ dinv,
                                                    int* __restrict__ bsum, int n) {
    __shared__ int s[256];
    int tid = threadIdx.x;
    int i = blockIdx.x * 256 + tid;
    int v = 0;
    if (i < n) {
        unsigned long long pk = packed[i];
        v = (int)(pk >> CNT_SHIFT);
        cnt[i] = v;
        float sum = (float)((double)(pk & WSUM_MASK) * (1.0 / 4294967296.0));
        dinv[i] = rsqrtf(sum);   // sum >= 1 always
    }
    s[tid] = v;
    __syncthreads();
    #pragma unroll
    for (int off = 128; off > 0; off >>= 1) {
        if (tid < off) s[tid] += s[tid + off];
        __syncthreads();
    }
    if (tid == 0) bsum[blockIdx.x] = s[0];
}

__global__ __launch_bounds__(512) void scan2_kernel(int* __restrict__ bsum, int nb) {
    __shared__ int s[512];
    int tid = threadIdx.x;
    int v = (tid < nb) ? bsum[tid] : 0;
    s[tid] = v;
    __syncthreads();
    #pragma unroll
    for (int off = 1; off < 512; off <<= 1) {
        int t = s[tid];
        int u = (tid >= off) ? s[tid - off] : 0;
        __syncthreads();
        s[tid] = t + u;
        __syncthreads();
    }
    if (tid < nb) bsum[tid] = (tid == 0) ? 0 : s[tid - 1];
}

__global__ __launch_bounds__(256) void scan3_kernel(const int* __restrict__ cnt,
                                                    const int* __restrict__ bsum,
                                                    int* __restrict__ rowptr, int n) {
    __shared__ int s[256];
    int tid = threadIdx.x;
    int i = blockIdx.x * 256 + tid;
    int v = (i < n) ? cnt[i] : 0;
    s[tid] = v;
    __syncthreads();
    #pragma unroll
    for (int off = 1; off < 256; off <<= 1) {
        int t = s[tid];
        int u = (tid >= off) ? s[tid - off] : 0;
        __syncthreads();
        s[tid] = t + u;
        __syncthreads();
    }
    if (i < n) rowptr[i] = bsum[blockIdx.x] + s[tid] - v;
    if (i == 0) rowptr[n] = N_EDGES;
}

// interleaved edge record: low dword = src, high dword = norm bits
__global__ void place_kernel(const int* __restrict__ src, const int* __restrict__ dst,
                             const float* __restrict__ w, const float* __restrict__ dinv,
                             const int* __restrict__ rowptr, const int* __restrict__ rank,
                             unsigned long long* __restrict__ edges, int E) {
    int e = blockIdx.x * blockDim.x + threadIdx.x;
    if (e < E) {
        int s = src[e], d = dst[e];
        int pos = rowptr[d] + rank[e];
        float nrm = dinv[s] * w[e] * dinv[d];
        unsigned long long rec = ((unsigned long long)__float_as_uint(nrm) << 32)
                               | (unsigned int)s;
        edges[pos] = rec;
    }
}

// ---------------- MFMA GEMM: H(bf16) = A @ W,  K=128 fixed ----------------
// Block: 128 rows x FOUT cols, 256 threads (4 waves x 32 rows).
// W split hi/lo bf16 into LDS, transposed n-major, stride 136 shorts.
// AF32: A is f32 flat -> in-register split, 3rd pass Alo@Whi recovers f32 accuracy.
// !AF32: A is bf16 in SHARDED layout [8][N][16] (shard = feat>>4).
// SHOUT: H written sharded [8][N][16]; else flat row-major stride HSTRIDE.

#define BSTR 136
#define SHSTR ((size_t)N_NODES * 16)   // shard stride in shorts

template<int NCT, int FOUT, int HSTRIDE, bool AF32, bool SHOUT>
__global__ __launch_bounds__(256) void gemm_mfma_kernel(
        const void* __restrict__ Ain, const float* __restrict__ W,
        unsigned short* __restrict__ Hout, int M) {
    __shared__ unsigned short sBhi[NCT * 16 * BSTR];
    __shared__ unsigned short sBlo[NCT * 16 * BSTR];
    int tid = threadIdx.x;

    if (FOUT != NCT * 16) {   // zero-pad unused B columns
        unsigned int* z0 = (unsigned int*)sBhi;
        unsigned int* z1 = (unsigned int*)sBlo;
        for (int i = tid; i < NCT * 16 * BSTR / 2; i += 256) { z0[i] = 0u; z1[i] = 0u; }
        __syncthreads();
    }
    // stage W (K=128 x FOUT, row-major) -> split bf16, transposed [n][k]
    for (int i = tid; i < 128 * FOUT; i += 256) {
        int k = i / FOUT, n = i - k * FOUT;
        float v = W[i];
        unsigned short hi = f2bf(v);
        unsigned short lo = f2bf(v - bf2f(hi));
        sBhi[n * BSTR + k] = hi;
        sBlo[n * BSTR + k] = lo;
    }
    __syncthreads();

    int lane = tid & 63;
    int m16 = lane & 15;
    int q = lane >> 4;
    int wv = tid >> 6;
    int wbase = blockIdx.x * 128 + wv * 32;

    // A fragments: 2 row-tiles x 4 k-steps, from global
    short8 afr[2][4];
    short8 alo[2][4];
    #pragma unroll
    for (int mt = 0; mt < 2; mt++) {
        int row = wbase + mt * 16 + m16;
        row = (row < M) ? row : (M - 1);   // clamp: no OOB fault, stores guarded
        if (AF32) {
            const float* ar = (const float*)Ain + (size_t)row * 128;
            #pragma unroll
            for (int kt = 0; kt < 4; kt++) {
                const float* p = ar + kt * 32 + q * 8;
                float4 a = *(const float4*)p;
                float4 b = *(const float4*)(p + 4);
                float vv[8] = {a.x, a.y, a.z, a.w, b.x, b.y, b.z, b.w};
                short8 h, l;
                #pragma unroll
                for (int j = 0; j < 8; j++) {
                    unsigned short hb = f2bf(vv[j]);
                    h[j] = (short)hb;
                    l[j] = (short)f2bf(vv[j] - bf2f(hb));
                }
                afr[mt][kt] = h;
                alo[mt][kt] = l;
            }
        } else {
            // sharded bf16 A: feature f = kt*32 + q*8 -> shard f>>4 = kt*2 + (q>>1),
            // within-shard offset (q&1)*8
            const unsigned short* ar = (const unsigned short*)Ain;
            #pragma unroll
            for (int kt = 0; kt < 4; kt++) {
                int shard = kt * 2 + (q >> 1);
                afr[mt][kt] = *(const short8*)(ar + (size_t)shard * SHSTR
                                               + (size_t)row * 16 + (q & 1) * 8);
            }
        }
    }

    f32x4 acc[2][NCT] = {};
    #pragma unroll
    for (int kt = 0; kt < 4; kt++) {
        #pragma unroll
        for (int ct = 0; ct < NCT; ct++) {
            const unsigned short* bp = &sBhi[(ct * 16 + m16) * BSTR + kt * 32 + q * 8];
            short8 bh = *(const short8*)bp;
            short8 bl = *(const short8*)&sBlo[(ct * 16 + m16) * BSTR + kt * 32 + q * 8];
            #pragma unroll
            for (int mt = 0; mt < 2; mt++) {
                acc[mt][ct] = __builtin_amdgcn_mfma_f32_16x16x32_bf16(afr[mt][kt], bh, acc[mt][ct], 0, 0, 0);
                acc[mt][ct] = __builtin_amdgcn_mfma_f32_16x16x32_bf16(afr[mt][kt], bl, acc[mt][ct], 0, 0, 0);
                if (AF32)
                    acc[mt][ct] = __builtin_amdgcn_mfma_f32_16x16x32_bf16(alo[mt][kt], bh, acc[mt][ct], 0, 0, 0);
            }
        }
    }

    // epilogue: C/D layout col=lane&15, row=(lane>>4)*4+reg
    #pragma unroll
    for (int mt = 0; mt < 2; mt++) {
        #pragma unroll
        for (int ct = 0; ct < NCT; ct++) {
            int col = ct * 16 + m16;
            if (!SHOUT && FOUT != NCT * 16 && col >= FOUT) continue;
            #pragma unroll
            for (int r = 0; r < 4; r++) {
                int row = wbase + mt * 16 + q * 4 + r;
                if (row < M) {
                    if (SHOUT)
                        Hout[(size_t)ct * SHSTR + (size_t)row * 16 + m16] = f2bf(acc[mt][ct][r]);
                    else
                        Hout[(size_t)row * HSTRIDE + col] = f2bf(acc[mt][ct][r]);
                }
            }
        }
    }
}

// ---------------- Aggregation F=128, feature-sharded ----------------
// H sharded [8][N][8 dwords] (16 bf16 feats per shard, 32 B/node/shard).
// Block bid: shard = bid&7, chunk = bid>>3. Round-robin dispatch pins shard s
// to XCD s -> 3.2 MB shard slice becomes L2-resident; H gathers turn into L2
// hits. Edge list streamed non-temporally (read once per XCD, 8x total, but
// sequential + LLC-resident). Per wave: 2 nodes; 8 edge-slot groups x 8 lanes
// (dword each = 2 feats); predicated slots (w=0, src=node) keep 16 rows in
// flight, no serial tail. Reduce: shfl_xor 8/16/32; lanes 0-7 store 32 B.

template<bool RELU>
__global__ __launch_bounds__(256) void gather128sh_kernel(
        const unsigned int* __restrict__ Hsh,               // [8][N*8] dwords
        const int* __restrict__ rowptr,
        const unsigned long long* __restrict__ edges,       // (src, normbits)
        const float* __restrict__ dinv, const float* __restrict__ bias,
        unsigned int* __restrict__ outsh, int n) {          // [8][N*8] dwords
    int s = blockIdx.x & 7;
    int chunk = blockIdx.x >> 3;
    int wave = threadIdx.x >> 6;
    int lane = threadIdx.x & 63;
    int g = lane >> 3;          // edge-slot group 0..7
    int l = lane & 7;           // dword within 32-B row segment
    const unsigned int* Hs = Hsh + (size_t)s * (N_NODES * 8);
    unsigned int* Os = outsh + (size_t)s * (N_NODES * 8);

    #pragma unroll
    for (int i = 0; i < 2; i++) {
        int node = chunk * 8 + wave * 2 + i;
        if (node >= n) return;
        int beg = __builtin_amdgcn_readfirstlane(rowptr[node]);
        int end = __builtin_amdgcn_readfirstlane(rowptr[node + 1]);
        int deg = end - beg;
        float di = dinv[node];
        unsigned int us = Hs[(size_t)node * 8 + l];   // self row segment
        float ws = (g == 0) ? di * di : 0.f;
        float ax = 0.f, ay = 0.f;

        for (int base = 0; base < deg; base += 16) {
            #pragma unroll
            for (int u = 0; u < 2; u++) {
                int slot = base + u * 8 + g;
                bool real = slot < deg;
                unsigned long long rec =
                    __builtin_nontemporal_load(&edges[real ? (beg + slot) : beg]);
                int src = real ? (int)(unsigned int)rec : node;
                float w = real ? __uint_as_float((unsigned int)(rec >> 32)) : 0.f;
                unsigned int q = Hs[(size_t)src * 8 + l];
                ax += w * bflo(q);
                ay += w * bfhi(q);
            }
        }
        ax += ws * bflo(us);
        ay += ws * bfhi(us);

        ax += __shfl_xor(ax, 8);  ay += __shfl_xor(ay, 8);
        ax += __shfl_xor(ax, 16); ay += __shfl_xor(ay, 16);
        ax += __shfl_xor(ax, 32); ay += __shfl_xor(ay, 32);

        if (lane < 8) {
            float2 bv = ((const float2*)bias)[s * 8 + l];
            ax += bv.x; ay += bv.y;
            if (RELU) { ax = fmaxf(ax, 0.f); ay = fmaxf(ay, 0.f); }
            unsigned int pk = (unsigned int)f2bf(ax) | ((unsigned int)f2bf(ay) << 16);
            __builtin_nontemporal_store(pk, &Os[(size_t)node * 8 + l]);
        }
    }
}

// F=40 (bf16 H, stride 32 dwords, 20 used): one wave/node, 3x 20-lane groups,
// predicated 6-slot iterations, shfl reduce, lanes 0-19 store f32 float2.
__global__ __launch_bounds__(256) void gather40v2_kernel(
        const unsigned int* __restrict__ H,   // N x 32 dwords (20 used)
        const int* __restrict__ rowptr,
        const unsigned long long* __restrict__ edges,
        const float* __restrict__ dinv, const float* __restrict__ bias,
        float* __restrict__ out, int n) {
    int wave = threadIdx.x >> 6;
    int lane = threadIdx.x & 63;
    int node = blockIdx.x * 4 + wave;
    if (node >= n) return;
    int beg = __builtin_amdgcn_readfirstlane(rowptr[node]);
    int end = __builtin_amdgcn_readfirstlane(rowptr[node + 1]);
    int deg = end - beg;
    float di = dinv[node];
    int g = lane / 20;            // 0..3 (g==3: lanes 60-63, always predicated off)
    int sl = lane - g * 20;
    bool gv = g < 3;
    int slcl = gv ? sl : 0;

    unsigned int us = H[(size_t)node * 32 + slcl];
    float ws = (g == 0) ? di * di : 0.f;
    float ax = 0.f, ay = 0.f;

    for (int base = 0; base < deg; base += 6) {
        #pragma unroll
        for (int u = 0; u < 2; u++) {
            int slot = base + g * 2 + u;
            bool real = gv && (slot < deg);
            unsigned long long rec = edges[real ? (beg + slot) : beg];
            int s  = real ? (int)(unsigned int)rec : node;
            float w = real ? __uint_as_float((unsigned int)(rec >> 32)) : 0.f;
            unsigned int uu = H[(size_t)s * 32 + slcl];
            ax += w * bflo(uu);
            ay += w * bfhi(uu);
        }
    }
    ax += ws * bflo(us);
    ay += ws * bfhi(us);

    // reduce groups 1,2 into group 0 (read original values before updating)
    float ax1 = __shfl(ax, lane + 20), ay1 = __shfl(ay, lane + 20);
    float ax2 = __shfl(ax, lane + 40), ay2 = __shfl(ay, lane + 40);
    if (lane < 20) {
        ax += ax1 + ax2;
        ay += ay1 + ay2;
        float2 bv = ((const float2*)bias)[lane];
        ax += bv.x; ay += bv.y;
        *(float2*)&out[(size_t)node * 40 + 2 * lane] = make_float2(ax, ay);
    }
}

// ---------------- launch ----------------

extern "C" void kernel_launch(void* const* d_in, const int* in_sizes, int n_in,
                              void* d_out, int out_size, void* d_ws, size_t ws_size,
                              hipStream_t stream) {
    const float* x  = (const float*)d_in[0];
    const int*   ei = (const int*)d_in[1];
    const float* ew = (const float*)d_in[2];
    const float* W1 = (const float*)d_in[3];
    const float* b1 = (const float*)d_in[4];
    const float* W2 = (const float*)d_in[5];
    const float* b2 = (const float*)d_in[6];
    const float* W3 = (const float*)d_in[7];
    const float* b3 = (const float*)d_in[8];
    float* out = (float*)d_out;

    const int N = N_NODES, E = N_EDGES;
    const int* src = ei;
    const int* dst = ei + E;

    char* p = (char*)d_ws;
    unsigned long long* packed = (unsigned long long*)p; p += 800000;   // N u64
    float* dinv   = (float*)p; p += 400000;
    int*   cnt    = (int*)p;   p += 400000;
    int*   rowptr = (int*)p;   p += 400016;
    int*   bsum   = (int*)p;   p += 2048;
    int*   rank   = (int*)p;   p += 6400000;                            // E i32
    unsigned long long* edges = (unsigned long long*)p; p += 12800000;  // E u64
    void*  A      = (void*)p;  p += (size_t)N * 128 * 2;                // bf16 H (sharded or flat)
    void*  B      = (void*)p;                                           // bf16 layer output (sharded)

    int nb = (N + 255) / 256;
    int eb = (E + 255) / 256;

    init_packed_kernel<<<nb, 256, 0, stream>>>(packed, N);
    edge_pass1_kernel<<<eb, 256, 0, stream>>>(dst, ew, packed, rank, E);
    scan1_kernel<<<SCAN_NB, 256, 0, stream>>>(packed, cnt, dinv, bsum, N);
    scan2_kernel<<<1, 512, 0, stream>>>(bsum, SCAN_NB);
    scan3_kernel<<<SCAN_NB, 256, 0, stream>>>(cnt, bsum, rowptr, N);
    place_kernel<<<eb, 256, 0, stream>>>(src, dst, ew, dinv, rowptr, rank, edges, E);

    int gemmb = (N + 127) / 128;   // 782
    int gshb = 8 * ((N + 7) / 8);  // 100000 blocks: shard = bid&7, chunk = bid>>3
    int gb = (N + 3) / 4;

    // layer 1: A(bf16, sharded) = x(f32)@W1  [3-pass split]
    gemm_mfma_kernel<8, 128, 128, true, true><<<gemmb, 256, 0, stream>>>(x, W1, (unsigned short*)A, N);
    gather128sh_kernel<true><<<gshb, 256, 0, stream>>>((const unsigned int*)A, rowptr, edges, dinv, b1, (unsigned int*)B, N);
    // layer 2: sharded bf16 A in, sharded out, 2-pass W split
    gemm_mfma_kernel<8, 128, 128, false, true><<<gemmb, 256, 0, stream>>>(B, W2, (unsigned short*)A, N);
    gather128sh_kernel<true><<<gshb, 256, 0, stream>>>((const unsigned int*)A, rowptr, edges, dinv, b2, (unsigned int*)B, N);
    // layer 3: sharded A in, flat H3 out (FOUT=40 padded to 48 cols, stride 64 shorts)
    gemm_mfma_kernel<3, 40, 64, false, false><<<gemmb, 256, 0, stream>>>(B, W3, (unsigned short*)A, N);
    gather40v2_kernel<<<gb, 256, 0, stream>>>((const unsigned int*)A, rowptr, edges, dinv, b3, out, N);
}

// Round 3
// 544.148 us; speedup vs baseline: 1.6688x; 1.6688x over previous
//
#include <hip/hip_runtime.h>

#define N_NODES 100000
#define N_EDGES 1600000
#define SCAN_NB ((N_NODES + 255) / 256)   // 391

// packed degree: bits 63..52 = count, bits 51..0 = sum(w) in 2^-32 fixed point
#define CNT_SHIFT 52
#define WSUM_MASK ((1ULL << 52) - 1)

typedef __attribute__((ext_vector_type(8))) short short8;   // MFMA A/B frag (8 bf16)
typedef __attribute__((ext_vector_type(4))) float f32x4;    // MFMA C/D frag

__device__ inline unsigned short f2bf(float f) {   // round-to-nearest-even
    unsigned int u = __float_as_uint(f);
    u += 0x7FFFu + ((u >> 16) & 1u);
    return (unsigned short)(u >> 16);
}
__device__ inline float bflo(unsigned int u) { return __uint_as_float(u << 16); }
__device__ inline float bfhi(unsigned int u) { return __uint_as_float(u & 0xFFFF0000u); }
__device__ inline float bf2f(unsigned short h) { return __uint_as_float((unsigned int)h << 16); }

// ---------------- CSR build ----------------
// packed[] zeroed by hipMemsetAsync; self-loop (weight 1.0) folded into scan1.

__global__ void edge_pass1_kernel(const int* __restrict__ dst, const float* __restrict__ w,
                                  unsigned long long* __restrict__ packed, int E) {
    int e = blockIdx.x * blockDim.x + threadIdx.x;
    if (e < E) {
        int d = dst[e];
        unsigned long long inc = (1ULL << CNT_SHIFT)
                               + (unsigned long long)((double)w[e] * 4294967296.0);
        atomicAdd(&packed[d], inc);   // fire-and-forget: no return value used
    }
}

// scan1 fused with extract: packed -> cnt, dinv, block sums
__global__ __launch_bounds__(256) void scan1_kernel(const unsigned long long* __restrict__ packed,
                                                    int* __restrict__ cnt, float* __restrict__ dinv,
                                                    int* __restrict__ bsum, int n) {
    __shared__ int s[256];
    int tid = threadIdx.x;
    int i = blockIdx.x * 256 + tid;
    int v = 0;
    if (i < n) {
        unsigned long long pk = packed[i];
        v = (int)(pk >> CNT_SHIFT);
        cnt[i] = v;
        // + 1.0 : self-loop weight (packed[] started at zero)
        float sum = (float)((double)(pk & WSUM_MASK) * (1.0 / 4294967296.0) + 1.0);
        dinv[i] = rsqrtf(sum);
    }
    s[tid] = v;
    __syncthreads();
    #pragma unroll
    for (int off = 128; off > 0; off >>= 1) {
        if (tid < off) s[tid] += s[tid + off];
        __syncthreads();
    }
    if (tid == 0) bsum[blockIdx.x] = s[0];
}

// scan3 (absorbs old scan2): each block reduces bsum[0..bid-1] itself, then
// block-local inclusive scan of cnt. Writes rowptr AND cursor (cursor aliases
// the cnt array — each thread reads cnt[i] before overwriting it).
__global__ __launch_bounds__(256) void scan3_kernel(int* __restrict__ cntcur,
                                                    const int* __restrict__ bsum,
                                                    int* __restrict__ rowptr, int n) {
    __shared__ int s[256];
    __shared__ int pref;
    int tid = threadIdx.x;
    int acc = 0;
    for (int j = tid; j < (int)blockIdx.x; j += 256) acc += bsum[j];
    s[tid] = acc;
    __syncthreads();
    #pragma unroll
    for (int off = 128; off > 0; off >>= 1) {
        if (tid < off) s[tid] += s[tid + off];
        __syncthreads();
    }
    if (tid == 0) pref = s[0];
    __syncthreads();

    int i = blockIdx.x * 256 + tid;
    int v = (i < n) ? cntcur[i] : 0;
    s[tid] = v;
    __syncthreads();
    #pragma unroll
    for (int off = 1; off < 256; off <<= 1) {
        int t = s[tid];
        int u = (tid >= off) ? s[tid - off] : 0;
        __syncthreads();
        s[tid] = t + u;
        __syncthreads();
    }
    if (i < n) {
        int rp = pref + s[tid] - v;
        rowptr[i] = rp;
        cntcur[i] = rp;   // cursor for place_kernel
    }
    if (i == 0) rowptr[n] = N_EDGES;
}

// interleaved edge record: low dword = src, high dword = norm bits
// slot via atomic cursor (replaces the old rank array)
__global__ void place_kernel(const int* __restrict__ src, const int* __restrict__ dst,
                             const float* __restrict__ w, const float* __restrict__ dinv,
                             int* __restrict__ cursor,
                             unsigned long long* __restrict__ edges, int E) {
    int e = blockIdx.x * blockDim.x + threadIdx.x;
    if (e < E) {
        int s = src[e], d = dst[e];
        int pos = atomicAdd(&cursor[d], 1);
        float nrm = dinv[s] * w[e] * dinv[d];
        unsigned long long rec = ((unsigned long long)__float_as_uint(nrm) << 32)
                               | (unsigned int)s;
        edges[pos] = rec;
    }
}

// ---------------- MFMA GEMM: H(bf16) = A @ W,  K=128 fixed ----------------
// Block: 128 rows x FOUT cols, 256 threads (4 waves x 32 rows).
// A-fragments loaded straight from global (16B/lane). W split hi/lo bf16 into LDS,
// transposed n-major, stride 136 shorts (16B-aligned frags, uniform 8-way b128).
// AF32: A is f32 -> in-register split, 3rd pass Alo@Whi recovers f32 accuracy.
// PLANES: FOUT=40 output split planeA [N][32] shorts + planeB [N][8] shorts
// (gather40 then fetches exactly 1 line/row from planeA; planeB is L2-resident).

#define BSTR 136

template<int NCT, int FOUT, int HSTRIDE, bool AF32, bool PLANES>
__global__ __launch_bounds__(256) void gemm_mfma_kernel(
        const void* __restrict__ Ain, const float* __restrict__ W,
        unsigned short* __restrict__ Hout, int M) {
    __shared__ unsigned short sBhi[NCT * 16 * BSTR];
    __shared__ unsigned short sBlo[NCT * 16 * BSTR];
    int tid = threadIdx.x;

    if (FOUT != NCT * 16) {   // zero-pad unused B columns
        unsigned int* z0 = (unsigned int*)sBhi;
        unsigned int* z1 = (unsigned int*)sBlo;
        for (int i = tid; i < NCT * 16 * BSTR / 2; i += 256) { z0[i] = 0u; z1[i] = 0u; }
        __syncthreads();
    }
    // stage W (K=128 x FOUT, row-major) -> split bf16, transposed [n][k]
    for (int i = tid; i < 128 * FOUT; i += 256) {
        int k = i / FOUT, n = i - k * FOUT;
        float v = W[i];
        unsigned short hi = f2bf(v);
        unsigned short lo = f2bf(v - bf2f(hi));
        sBhi[n * BSTR + k] = hi;
        sBlo[n * BSTR + k] = lo;
    }
    __syncthreads();

    int lane = tid & 63;
    int m16 = lane & 15;
    int q = lane >> 4;
    int wv = tid >> 6;
    int wbase = blockIdx.x * 128 + wv * 32;

    // A fragments: 2 row-tiles x 4 k-steps, from global
    short8 afr[2][4];
    short8 alo[2][4];
    #pragma unroll
    for (int mt = 0; mt < 2; mt++) {
        int row = wbase + mt * 16 + m16;
        row = (row < M) ? row : (M - 1);   // clamp: no OOB fault, stores guarded
        if (AF32) {
            const float* ar = (const float*)Ain + (size_t)row * 128;
            #pragma unroll
            for (int kt = 0; kt < 4; kt++) {
                const float* p = ar + kt * 32 + q * 8;
                float4 a = *(const float4*)p;
                float4 b = *(const float4*)(p + 4);
                float vv[8] = {a.x, a.y, a.z, a.w, b.x, b.y, b.z, b.w};
                short8 h, l;
                #pragma unroll
                for (int j = 0; j < 8; j++) {
                    unsigned short hb = f2bf(vv[j]);
                    h[j] = (short)hb;
                    l[j] = (short)f2bf(vv[j] - bf2f(hb));
                }
                afr[mt][kt] = h;
                alo[mt][kt] = l;
            }
        } else {
            const unsigned short* ar = (const unsigned short*)Ain + (size_t)row * 128;
            #pragma unroll
            for (int kt = 0; kt < 4; kt++) {
                afr[mt][kt] = *(const short8*)(ar + kt * 32 + q * 8);
            }
        }
    }

    f32x4 acc[2][NCT] = {};
    #pragma unroll
    for (int kt = 0; kt < 4; kt++) {
        #pragma unroll
        for (int ct = 0; ct < NCT; ct++) {
            const unsigned short* bp = &sBhi[(ct * 16 + m16) * BSTR + kt * 32 + q * 8];
            short8 bh = *(const short8*)bp;
            short8 bl = *(const short8*)&sBlo[(ct * 16 + m16) * BSTR + kt * 32 + q * 8];
            #pragma unroll
            for (int mt = 0; mt < 2; mt++) {
                acc[mt][ct] = __builtin_amdgcn_mfma_f32_16x16x32_bf16(afr[mt][kt], bh, acc[mt][ct], 0, 0, 0);
                acc[mt][ct] = __builtin_amdgcn_mfma_f32_16x16x32_bf16(afr[mt][kt], bl, acc[mt][ct], 0, 0, 0);
                if (AF32)
                    acc[mt][ct] = __builtin_amdgcn_mfma_f32_16x16x32_bf16(alo[mt][kt], bh, acc[mt][ct], 0, 0, 0);
            }
        }
    }

    // epilogue: C/D layout col=lane&15, row=(lane>>4)*4+reg
    unsigned short* HoutB = Hout + (size_t)N_NODES * 32;   // planeB (PLANES only)
    #pragma unroll
    for (int mt = 0; mt < 2; mt++) {
        #pragma unroll
        for (int ct = 0; ct < NCT; ct++) {
            int col = ct * 16 + m16;
            if (!PLANES && FOUT != NCT * 16 && col >= FOUT) continue;
            #pragma unroll
            for (int r = 0; r < 4; r++) {
                int row = wbase + mt * 16 + q * 4 + r;
                if (row < M) {
                    if (PLANES) {
                        if (col < 32)
                            Hout[(size_t)row * 32 + col] = f2bf(acc[mt][ct][r]);
                        else if (col < FOUT)
                            HoutB[(size_t)row * 8 + (col - 32)] = f2bf(acc[mt][ct][r]);
                    } else {
                        Hout[(size_t)row * HSTRIDE + col] = f2bf(acc[mt][ct][r]);
                    }
                }
            }
        }
    }
}

// ---------------- Aggregation F=128 (bf16 H, bf16 out): one wave/node ----------------
// (round-0 proven structure: 82 us, ~3.85 TB/s LLC-fill — measured pattern roofline)

template<bool RELU>
__global__ __launch_bounds__(256) void gather128bf_kernel(
        const unsigned int* __restrict__ H,                 // N x 64 dwords (bf16x2)
        const int* __restrict__ rowptr,
        const unsigned long long* __restrict__ edges,       // (src, normbits)
        const float* __restrict__ dinv, const float* __restrict__ bias,
        unsigned int* __restrict__ out, int n) {            // N x 64 dwords (bf16x2)
    int wave = threadIdx.x >> 6;
    int lane = threadIdx.x & 63;
    int node = blockIdx.x * 4 + wave;
    if (node >= n) return;
    int beg = __builtin_amdgcn_readfirstlane(rowptr[node]);
    int end = __builtin_amdgcn_readfirstlane(rowptr[node + 1]);
    float ax = 0.f, ay = 0.f;
    int e = beg;
    for (; e + 7 < end; e += 8) {
        int s[8]; float w[8]; unsigned int u[8];
        #pragma unroll
        for (int i = 0; i < 8; i++) {
            unsigned long long rec = edges[e + i];
            s[i] = (int)(unsigned int)rec;
            w[i] = __uint_as_float((unsigned int)(rec >> 32));
        }
        #pragma unroll
        for (int i = 0; i < 8; i++) { u[i] = H[(size_t)s[i] * 64 + lane]; }
        #pragma unroll
        for (int i = 0; i < 8; i++) {
            ax += w[i] * bflo(u[i]);
            ay += w[i] * bfhi(u[i]);
        }
    }
    for (; e < end; e++) {
        unsigned long long rec = edges[e];
        float w0 = __uint_as_float((unsigned int)(rec >> 32));
        unsigned int u = H[(size_t)(unsigned int)rec * 64 + lane];
        ax += w0 * bflo(u);
        ay += w0 * bfhi(u);
    }
    float di = dinv[node];
    float sw = di * di;
    unsigned int us = H[(size_t)node * 64 + lane];
    ax += sw * bflo(us);
    ay += sw * bfhi(us);
    float2 bv = ((const float2*)bias)[lane];
    ax += bv.x; ay += bv.y;
    if (RELU) { ax = fmaxf(ax, 0.f); ay = fmaxf(ay, 0.f); }
    unsigned int pk = (unsigned int)f2bf(ax) | ((unsigned int)f2bf(ay) << 16);
    out[(size_t)node * 64 + lane] = pk;
}

// F=40 gather over plane-split H3: planeA [N][16 dwords] (64 B = exactly 1 line
// per row), planeB [N][4 dwords] (1.6 MB -> L2-resident). One wave/node,
// 3x 20-lane groups, predicated 6-slot iterations, shfl reduce, f32 out.
__global__ __launch_bounds__(256) void gather40p_kernel(
        const unsigned int* __restrict__ H,   // planeA; planeB at H + N*16
        const int* __restrict__ rowptr,
        const unsigned long long* __restrict__ edges,
        const float* __restrict__ dinv, const float* __restrict__ bias,
        float* __restrict__ out, int n) {
    int wave = threadIdx.x >> 6;
    int lane = threadIdx.x & 63;
    int node = blockIdx.x * 4 + wave;
    if (node >= n) return;
    int beg = __builtin_amdgcn_readfirstlane(rowptr[node]);
    int end = __builtin_amdgcn_readfirstlane(rowptr[node + 1]);
    int deg = end - beg;
    float di = dinv[node];
    int g = lane / 20;            // 0..3 (g==3: lanes 60-63, always predicated off)
    int sl = lane - g * 20;
    bool gv = g < 3;
    int slcl = gv ? sl : 0;

    // per-lane plane addressing: row r -> base + r*mult + off
    size_t pb_base = (size_t)N_NODES * 16;
    int  mult = (slcl < 16) ? 16 : 4;
    size_t offc = (slcl < 16) ? (size_t)slcl : pb_base + (size_t)(slcl - 16);

    unsigned int us = H[(size_t)node * mult + offc];
    float ws = (g == 0) ? di * di : 0.f;
    float ax = 0.f, ay = 0.f;

    for (int base = 0; base < deg; base += 6) {
        #pragma unroll
        for (int u = 0; u < 2; u++) {
            int slot = base + g * 2 + u;
            bool real = gv && (slot < deg);
            unsigned long long rec = edges[real ? (beg + slot) : beg];
            int s  = real ? (int)(unsigned int)rec : node;
            float w = real ? __uint_as_float((unsigned int)(rec >> 32)) : 0.f;
            unsigned int uu = H[(size_t)s * mult + offc];
            ax += w * bflo(uu);
            ay += w * bfhi(uu);
        }
    }
    ax += ws * bflo(us);
    ay += ws * bfhi(us);

    // reduce groups 1,2 into group 0 (read original values before updating)
    float ax1 = __shfl(ax, lane + 20), ay1 = __shfl(ay, lane + 20);
    float ax2 = __shfl(ax, lane + 40), ay2 = __shfl(ay, lane + 40);
    if (lane < 20) {
        ax += ax1 + ax2;
        ay += ay1 + ay2;
        float2 bv = ((const float2*)bias)[lane];
        ax += bv.x; ay += bv.y;
        *(float2*)&out[(size_t)node * 40 + 2 * lane] = make_float2(ax, ay);
    }
}

// ---------------- launch ----------------

extern "C" void kernel_launch(void* const* d_in, const int* in_sizes, int n_in,
                              void* d_out, int out_size, void* d_ws, size_t ws_size,
                              hipStream_t stream) {
    const float* x  = (const float*)d_in[0];
    const int*   ei = (const int*)d_in[1];
    const float* ew = (const float*)d_in[2];
    const float* W1 = (const float*)d_in[3];
    const float* b1 = (const float*)d_in[4];
    const float* W2 = (const float*)d_in[5];
    const float* b2 = (const float*)d_in[6];
    const float* W3 = (const float*)d_in[7];
    const float* b3 = (const float*)d_in[8];
    float* out = (float*)d_out;

    const int N = N_NODES, E = N_EDGES;
    const int* src = ei;
    const int* dst = ei + E;

    char* p = (char*)d_ws;
    unsigned long long* packed = (unsigned long long*)p; p += 800000;   // N u64
    float* dinv   = (float*)p; p += 400000;
    int*   cnt    = (int*)p;   p += 400000;                             // -> cursor after scan3
    int*   rowptr = (int*)p;   p += 400016;
    int*   bsum   = (int*)p;   p += 2048;
    unsigned long long* edges = (unsigned long long*)p; p += 12800000;  // E u64
    void*  A      = (void*)p;  p += (size_t)N * 128 * 2;                // bf16 H
    void*  B      = (void*)p;                                           // bf16 layer output

    int eb = (E + 255) / 256;

    hipMemsetAsync(packed, 0, (size_t)N * 8, stream);
    edge_pass1_kernel<<<eb, 256, 0, stream>>>(dst, ew, packed, E);
    scan1_kernel<<<SCAN_NB, 256, 0, stream>>>(packed, cnt, dinv, bsum, N);
    scan3_kernel<<<SCAN_NB, 256, 0, stream>>>(cnt, bsum, rowptr, N);
    place_kernel<<<eb, 256, 0, stream>>>(src, dst, ew, dinv, cnt, edges, E);

    int gemmb = (N + 127) / 128;   // 782
    int gb = (N + 3) / 4;

    // layer 1: A(bf16) = x(f32)@W1  [3-pass split]
    gemm_mfma_kernel<8, 128, 128, true, false><<<gemmb, 256, 0, stream>>>(x, W1, (unsigned short*)A, N);
    gather128bf_kernel<true><<<gb, 256, 0, stream>>>((const unsigned int*)A, rowptr, edges, dinv, b1, (unsigned int*)B, N);
    // layer 2: bf16 A, 2-pass W split
    gemm_mfma_kernel<8, 128, 128, false, false><<<gemmb, 256, 0, stream>>>(B, W2, (unsigned short*)A, N);
    gather128bf_kernel<true><<<gb, 256, 0, stream>>>((const unsigned int*)A, rowptr, edges, dinv, b2, (unsigned int*)B, N);
    // layer 3: FOUT=40, plane-split H3 (planeA [N][32] + planeB [N][8] shorts)
    gemm_mfma_kernel<3, 40, 0, false, true><<<gemmb, 256, 0, stream>>>(B, W3, (unsigned short*)A, N);
    gather40p_kernel<<<gb, 256, 0, stream>>>((const unsigned int*)A, rowptr, edges, dinv, b3, out, N);
}

// Round 4
// 503.941 us; speedup vs baseline: 1.8019x; 1.0798x over previous
//
#include <hip/hip_runtime.h>

#define N_NODES 100000
#define N_EDGES 1600000
#define SCAN_NB ((N_NODES + 255) / 256)   // 391

// packed degree: bits 63..52 = count, bits 51..0 = sum(w) in 2^-32 fixed point
#define CNT_SHIFT 52
#define WSUM_MASK ((1ULL << 52) - 1)

typedef __attribute__((ext_vector_type(8))) short short8;   // MFMA A/B frag (8 bf16)
typedef __attribute__((ext_vector_type(4))) float f32x4;    // MFMA C/D frag

__device__ inline unsigned short f2bf(float f) {   // round-to-nearest-even
    unsigned int u = __float_as_uint(f);
    u += 0x7FFFu + ((u >> 16) & 1u);
    return (unsigned short)(u >> 16);
}
__device__ inline float bflo(unsigned int u) { return __uint_as_float(u << 16); }
__device__ inline float bfhi(unsigned int u) { return __uint_as_float(u & 0xFFFF0000u); }
__device__ inline float bf2f(unsigned short h) { return __uint_as_float((unsigned int)h << 16); }

// ---------------- CSR build ----------------
// packed[] zeroed by hipMemsetAsync; self-loop (weight 1.0) folded into scan1.
// Two-phase rank scheme (measured best): pass1's atomic RETURN feeds rank[],
// place is a pure fire-and-forget scatter (no atomic -> no dependent-latency chain).

__global__ void edge_pass1_kernel(const int* __restrict__ dst, const float* __restrict__ w,
                                  unsigned long long* __restrict__ packed,
                                  int* __restrict__ rank, int E) {
    int e = blockIdx.x * blockDim.x + threadIdx.x;
    if (e < E) {
        int d = dst[e];
        unsigned long long inc = (1ULL << CNT_SHIFT)
                               + (unsigned long long)((double)w[e] * 4294967296.0);
        unsigned long long old = atomicAdd(&packed[d], inc);
        rank[e] = (int)(old >> CNT_SHIFT);
    }
}

// scan1 fused with extract: packed -> cnt, dinv, block sums
__global__ __launch_bounds__(256) void scan1_kernel(const unsigned long long* __restrict__ packed,
                                                    int* __restrict__ cnt, float* __restrict__ dinv,
                                                    int* __restrict__ bsum, int n) {
    __shared__ int s[256];
    int tid = threadIdx.x;
    int i = blockIdx.x * 256 + tid;
    int v = 0;
    if (i < n) {
        unsigned long long pk = packed[i];
        v = (int)(pk >> CNT_SHIFT);
        cnt[i] = v;
        // + 1.0 : self-loop weight (packed[] started at zero)
        float sum = (float)((double)(pk & WSUM_MASK) * (1.0 / 4294967296.0) + 1.0);
        dinv[i] = rsqrtf(sum);
    }
    s[tid] = v;
    __syncthreads();
    #pragma unroll
    for (int off = 128; off > 0; off >>= 1) {
        if (tid < off) s[tid] += s[tid + off];
        __syncthreads();
    }
    if (tid == 0) bsum[blockIdx.x] = s[0];
}

// scan3 (absorbs old scan2): each block reduces bsum[0..bid-1] itself, then
// block-local inclusive scan of cnt -> rowptr.
__global__ __launch_bounds__(256) void scan3_kernel(const int* __restrict__ cnt,
                                                    const int* __restrict__ bsum,
                                                    int* __restrict__ rowptr, int n) {
    __shared__ int s[256];
    __shared__ int pref;
    int tid = threadIdx.x;
    int acc = 0;
    for (int j = tid; j < (int)blockIdx.x; j += 256) acc += bsum[j];
    s[tid] = acc;
    __syncthreads();
    #pragma unroll
    for (int off = 128; off > 0; off >>= 1) {
        if (tid < off) s[tid] += s[tid + off];
        __syncthreads();
    }
    if (tid == 0) pref = s[0];
    __syncthreads();

    int i = blockIdx.x * 256 + tid;
    int v = (i < n) ? cnt[i] : 0;
    s[tid] = v;
    __syncthreads();
    #pragma unroll
    for (int off = 1; off < 256; off <<= 1) {
        int t = s[tid];
        int u = (tid >= off) ? s[tid - off] : 0;
        __syncthreads();
        s[tid] = t + u;
        __syncthreads();
    }
    if (i < n) rowptr[i] = pref + s[tid] - v;
    if (i == 0) rowptr[n] = N_EDGES;
}

// interleaved edge record: low dword = src, high dword = norm bits
__global__ void place_kernel(const int* __restrict__ src, const int* __restrict__ dst,
                             const float* __restrict__ w, const float* __restrict__ dinv,
                             const int* __restrict__ rowptr, const int* __restrict__ rank,
                             unsigned long long* __restrict__ edges, int E) {
    int e = blockIdx.x * blockDim.x + threadIdx.x;
    if (e < E) {
        int s = src[e], d = dst[e];
        int pos = rowptr[d] + rank[e];
        float nrm = dinv[s] * w[e] * dinv[d];
        unsigned long long rec = ((unsigned long long)__float_as_uint(nrm) << 32)
                               | (unsigned int)s;
        edges[pos] = rec;
    }
}

// ---------------- MFMA GEMM: H(bf16) = A @ W,  K=128 fixed ----------------
// Block: 128 rows x FOUT cols, 256 threads (4 waves x 32 rows).
// A-fragments loaded straight from global (16B/lane). W split hi/lo bf16 into LDS,
// transposed n-major, stride 136 shorts (16B-aligned frags, uniform 8-way b128).
// AF32: A is f32 -> in-register split, 3rd pass Alo@Whi recovers f32 accuracy.
// PLANES: FOUT=40 output split planeA [N][32] shorts + planeB [N][8] shorts
// (gather40 then fetches exactly 1 line/row from planeA; planeB is L2-resident).

#define BSTR 136

template<int NCT, int FOUT, int HSTRIDE, bool AF32, bool PLANES>
__global__ __launch_bounds__(256) void gemm_mfma_kernel(
        const void* __restrict__ Ain, const float* __restrict__ W,
        unsigned short* __restrict__ Hout, int M) {
    __shared__ unsigned short sBhi[NCT * 16 * BSTR];
    __shared__ unsigned short sBlo[NCT * 16 * BSTR];
    int tid = threadIdx.x;

    if (FOUT != NCT * 16) {   // zero-pad unused B columns
        unsigned int* z0 = (unsigned int*)sBhi;
        unsigned int* z1 = (unsigned int*)sBlo;
        for (int i = tid; i < NCT * 16 * BSTR / 2; i += 256) { z0[i] = 0u; z1[i] = 0u; }
        __syncthreads();
    }
    // stage W (K=128 x FOUT, row-major) -> split bf16, transposed [n][k]
    for (int i = tid; i < 128 * FOUT; i += 256) {
        int k = i / FOUT, n = i - k * FOUT;
        float v = W[i];
        unsigned short hi = f2bf(v);
        unsigned short lo = f2bf(v - bf2f(hi));
        sBhi[n * BSTR + k] = hi;
        sBlo[n * BSTR + k] = lo;
    }
    __syncthreads();

    int lane = tid & 63;
    int m16 = lane & 15;
    int q = lane >> 4;
    int wv = tid >> 6;
    int wbase = blockIdx.x * 128 + wv * 32;

    // A fragments: 2 row-tiles x 4 k-steps, from global
    short8 afr[2][4];
    short8 alo[2][4];
    #pragma unroll
    for (int mt = 0; mt < 2; mt++) {
        int row = wbase + mt * 16 + m16;
        row = (row < M) ? row : (M - 1);   // clamp: no OOB fault, stores guarded
        if (AF32) {
            const float* ar = (const float*)Ain + (size_t)row * 128;
            #pragma unroll
            for (int kt = 0; kt < 4; kt++) {
                const float* p = ar + kt * 32 + q * 8;
                float4 a = *(const float4*)p;
                float4 b = *(const float4*)(p + 4);
                float vv[8] = {a.x, a.y, a.z, a.w, b.x, b.y, b.z, b.w};
                short8 h, l;
                #pragma unroll
                for (int j = 0; j < 8; j++) {
                    unsigned short hb = f2bf(vv[j]);
                    h[j] = (short)hb;
                    l[j] = (short)f2bf(vv[j] - bf2f(hb));
                }
                afr[mt][kt] = h;
                alo[mt][kt] = l;
            }
        } else {
            const unsigned short* ar = (const unsigned short*)Ain + (size_t)row * 128;
            #pragma unroll
            for (int kt = 0; kt < 4; kt++) {
                afr[mt][kt] = *(const short8*)(ar + kt * 32 + q * 8);
            }
        }
    }

    f32x4 acc[2][NCT] = {};
    #pragma unroll
    for (int kt = 0; kt < 4; kt++) {
        #pragma unroll
        for (int ct = 0; ct < NCT; ct++) {
            const unsigned short* bp = &sBhi[(ct * 16 + m16) * BSTR + kt * 32 + q * 8];
            short8 bh = *(const short8*)bp;
            short8 bl = *(const short8*)&sBlo[(ct * 16 + m16) * BSTR + kt * 32 + q * 8];
            #pragma unroll
            for (int mt = 0; mt < 2; mt++) {
                acc[mt][ct] = __builtin_amdgcn_mfma_f32_16x16x32_bf16(afr[mt][kt], bh, acc[mt][ct], 0, 0, 0);
                acc[mt][ct] = __builtin_amdgcn_mfma_f32_16x16x32_bf16(afr[mt][kt], bl, acc[mt][ct], 0, 0, 0);
                if (AF32)
                    acc[mt][ct] = __builtin_amdgcn_mfma_f32_16x16x32_bf16(alo[mt][kt], bh, acc[mt][ct], 0, 0, 0);
            }
        }
    }

    // epilogue: C/D layout col=lane&15, row=(lane>>4)*4+reg
    unsigned short* HoutB = Hout + (size_t)N_NODES * 32;   // planeB (PLANES only)
    #pragma unroll
    for (int mt = 0; mt < 2; mt++) {
        #pragma unroll
        for (int ct = 0; ct < NCT; ct++) {
            int col = ct * 16 + m16;
            if (!PLANES && FOUT != NCT * 16 && col >= FOUT) continue;
            #pragma unroll
            for (int r = 0; r < 4; r++) {
                int row = wbase + mt * 16 + q * 4 + r;
                if (row < M) {
                    if (PLANES) {
                        if (col < 32)
                            Hout[(size_t)row * 32 + col] = f2bf(acc[mt][ct][r]);
                        else if (col < FOUT)
                            HoutB[(size_t)row * 8 + (col - 32)] = f2bf(acc[mt][ct][r]);
                    } else {
                        Hout[(size_t)row * HSTRIDE + col] = f2bf(acc[mt][ct][r]);
                    }
                }
            }
        }
    }
}

// ---------------- Aggregation F=128 (bf16 H, bf16 out): one wave/node ----------------
// (round-0 proven structure: 82 us, ~3.85 TB/s LLC-fill — measured pattern roofline)

template<bool RELU>
__global__ __launch_bounds__(256) void gather128bf_kernel(
        const unsigned int* __restrict__ H,                 // N x 64 dwords (bf16x2)
        const int* __restrict__ rowptr,
        const unsigned long long* __restrict__ edges,       // (src, normbits)
        const float* __restrict__ dinv, const float* __restrict__ bias,
        unsigned int* __restrict__ out, int n) {            // N x 64 dwords (bf16x2)
    int wave = threadIdx.x >> 6;
    int lane = threadIdx.x & 63;
    int node = blockIdx.x * 4 + wave;
    if (node >= n) return;
    int beg = __builtin_amdgcn_readfirstlane(rowptr[node]);
    int end = __builtin_amdgcn_readfirstlane(rowptr[node + 1]);
    float ax = 0.f, ay = 0.f;
    int e = beg;
    for (; e + 7 < end; e += 8) {
        int s[8]; float w[8]; unsigned int u[8];
        #pragma unroll
        for (int i = 0; i < 8; i++) {
            unsigned long long rec = edges[e + i];
            s[i] = (int)(unsigned int)rec;
            w[i] = __uint_as_float((unsigned int)(rec >> 32));
        }
        #pragma unroll
        for (int i = 0; i < 8; i++) { u[i] = H[(size_t)s[i] * 64 + lane]; }
        #pragma unroll
        for (int i = 0; i < 8; i++) {
            ax += w[i] * bflo(u[i]);
            ay += w[i] * bfhi(u[i]);
        }
    }
    for (; e < end; e++) {
        unsigned long long rec = edges[e];
        float w0 = __uint_as_float((unsigned int)(rec >> 32));
        unsigned int u = H[(size_t)(unsigned int)rec * 64 + lane];
        ax += w0 * bflo(u);
        ay += w0 * bfhi(u);
    }
    float di = dinv[node];
    float sw = di * di;
    unsigned int us = H[(size_t)node * 64 + lane];
    ax += sw * bflo(us);
    ay += sw * bfhi(us);
    float2 bv = ((const float2*)bias)[lane];
    ax += bv.x; ay += bv.y;
    if (RELU) { ax = fmaxf(ax, 0.f); ay = fmaxf(ay, 0.f); }
    unsigned int pk = (unsigned int)f2bf(ax) | ((unsigned int)f2bf(ay) << 16);
    out[(size_t)node * 64 + lane] = pk;
}

// F=40 gather over plane-split H3: planeA [N][16 dwords] (64 B = exactly 1 line
// per row), planeB [N][4 dwords] (1.6 MB -> L2-resident). One wave/node,
// 3x 20-lane groups, predicated 6-slot iterations, shfl reduce, f32 out.
__global__ __launch_bounds__(256) void gather40p_kernel(
        const unsigned int* __restrict__ H,   // planeA; planeB at H + N*16
        const int* __restrict__ rowptr,
        const unsigned long long* __restrict__ edges,
        const float* __restrict__ dinv, const float* __restrict__ bias,
        float* __restrict__ out, int n) {
    int wave = threadIdx.x >> 6;
    int lane = threadIdx.x & 63;
    int node = blockIdx.x * 4 + wave;
    if (node >= n) return;
    int beg = __builtin_amdgcn_readfirstlane(rowptr[node]);
    int end = __builtin_amdgcn_readfirstlane(rowptr[node + 1]);
    int deg = end - beg;
    float di = dinv[node];
    int g = lane / 20;            // 0..3 (g==3: lanes 60-63, always predicated off)
    int sl = lane - g * 20;
    bool gv = g < 3;
    int slcl = gv ? sl : 0;

    // per-lane plane addressing: row r -> base + r*mult + off
    size_t pb_base = (size_t)N_NODES * 16;
    int  mult = (slcl < 16) ? 16 : 4;
    size_t offc = (slcl < 16) ? (size_t)slcl : pb_base + (size_t)(slcl - 16);

    unsigned int us = H[(size_t)node * mult + offc];
    float ws = (g == 0) ? di * di : 0.f;
    float ax = 0.f, ay = 0.f;

    for (int base = 0; base < deg; base += 6) {
        #pragma unroll
        for (int u = 0; u < 2; u++) {
            int slot = base + g * 2 + u;
            bool real = gv && (slot < deg);
            unsigned long long rec = edges[real ? (beg + slot) : beg];
            int s  = real ? (int)(unsigned int)rec : node;
            float w = real ? __uint_as_float((unsigned int)(rec >> 32)) : 0.f;
            unsigned int uu = H[(size_t)s * mult + offc];
            ax += w * bflo(uu);
            ay += w * bfhi(uu);
        }
    }
    ax += ws * bflo(us);
    ay += ws * bfhi(us);

    // reduce groups 1,2 into group 0 (read original values before updating)
    float ax1 = __shfl(ax, lane + 20), ay1 = __shfl(ay, lane + 20);
    float ax2 = __shfl(ax, lane + 40), ay2 = __shfl(ay, lane + 40);
    if (lane < 20) {
        ax += ax1 + ax2;
        ay += ay1 + ay2;
        float2 bv = ((const float2*)bias)[lane];
        ax += bv.x; ay += bv.y;
        *(float2*)&out[(size_t)node * 40 + 2 * lane] = make_float2(ax, ay);
    }
}

// ---------------- launch ----------------

extern "C" void kernel_launch(void* const* d_in, const int* in_sizes, int n_in,
                              void* d_out, int out_size, void* d_ws, size_t ws_size,
                              hipStream_t stream) {
    const float* x  = (const float*)d_in[0];
    const int*   ei = (const int*)d_in[1];
    const float* ew = (const float*)d_in[2];
    const float* W1 = (const float*)d_in[3];
    const float* b1 = (const float*)d_in[4];
    const float* W2 = (const float*)d_in[5];
    const float* b2 = (const float*)d_in[6];
    const float* W3 = (const float*)d_in[7];
    const float* b3 = (const float*)d_in[8];
    float* out = (float*)d_out;

    const int N = N_NODES, E = N_EDGES;
    const int* src = ei;
    const int* dst = ei + E;

    char* p = (char*)d_ws;
    unsigned long long* packed = (unsigned long long*)p; p += 800000;   // N u64
    float* dinv   = (float*)p; p += 400000;
    int*   cnt    = (int*)p;   p += 400000;
    int*   rowptr = (int*)p;   p += 400016;
    int*   bsum   = (int*)p;   p += 2048;
    int*   rank   = (int*)p;   p += 6400000;                            // E i32
    unsigned long long* edges = (unsigned long long*)p; p += 12800000;  // E u64
    void*  A      = (void*)p;  p += (size_t)N * 128 * 2;                // bf16 H
    void*  B      = (void*)p;                                           // bf16 layer output

    int eb = (E + 255) / 256;

    hipMemsetAsync(packed, 0, (size_t)N * 8, stream);
    edge_pass1_kernel<<<eb, 256, 0, stream>>>(dst, ew, packed, rank, E);
    scan1_kernel<<<SCAN_NB, 256, 0, stream>>>(packed, cnt, dinv, bsum, N);
    scan3_kernel<<<SCAN_NB, 256, 0, stream>>>(cnt, bsum, rowptr, N);
    place_kernel<<<eb, 256, 0, stream>>>(src, dst, ew, dinv, rowptr, rank, edges, E);

    int gemmb = (N + 127) / 128;   // 782
    int gb = (N + 3) / 4;

    // layer 1: A(bf16) = x(f32)@W1  [3-pass split]
    gemm_mfma_kernel<8, 128, 128, true, false><<<gemmb, 256, 0, stream>>>(x, W1, (unsigned short*)A, N);
    gather128bf_kernel<true><<<gb, 256, 0, stream>>>((const unsigned int*)A, rowptr, edges, dinv, b1, (unsigned int*)B, N);
    // layer 2: bf16 A, 2-pass W split
    gemm_mfma_kernel<8, 128, 128, false, false><<<gemmb, 256, 0, stream>>>(B, W2, (unsigned short*)A, N);
    gather128bf_kernel<true><<<gb, 256, 0, stream>>>((const unsigned int*)A, rowptr, edges, dinv, b2, (unsigned int*)B, N);
    // layer 3: FOUT=40, plane-split H3 (planeA [N][32] + planeB [N][8] shorts)
    gemm_mfma_kernel<3, 40, 0, false, true><<<gemmb, 256, 0, stream>>>(B, W3, (unsigned short*)A, N);
    gather40p_kernel<<<gb, 256, 0, stream>>>((const unsigned int*)A, rowptr, edges, dinv, b3, out, N);
}